// Round 10
// baseline (39.737 us; speedup 1.0000x reference)
//
#include <hip/hip_runtime.h>

// TransE 'rhs': pred[b,n] = MARGIN - ||(s+r)[b] - e[n]||_2. B=32,N=200k,D=64 fp32.
//
// R9 post-mortem: store evidence across rounds => HBM write granule >=512B;
// 256B per-block segments write every granule twice (WRITE_SIZE 50 vs 25.6MB
// ideal, in R5 AND R9). R10: persistent wave owns 256 consecutive n; outputs
// staged in LDS [32][256] f32; store phase = 32 x 1KB-contiguous instrs
// (pattern proven clean in R1/R2). e: 8KB 32-row tiles, DMA dbuf A/B,
// counted vmcnt(8) never draining mid-loop (R8 schedule). q hi+lo bf16,
// e hi-only, 8-MFMA/tile chain (R8 math, absmax 0.0625 validated).
// LDS 48KB -> 3 blocks/CU; grid 782 -> ~all-resident.

#define MARGIN 9.0f

typedef __attribute__((ext_vector_type(8)))  short bf16x8;
typedef __attribute__((ext_vector_type(16))) float f32x16;
typedef __attribute__((ext_vector_type(4)))  unsigned int u32x4;

typedef __attribute__((address_space(3))) void        lds_vp;
typedef __attribute__((address_space(1))) const void  glb_vp;

__global__ __launch_bounds__(64)
void transe10(const float* __restrict__ s_emb,
              const float* __restrict__ rel_emb,
              const float* __restrict__ emb_e,
              float* __restrict__ out, int N)
{
    __shared__ char  A[8192];
    __shared__ char  Bb[8192];
    __shared__ float oT[32 * 256];        // out staging [b][nlocal], 32 KB
    const int  lane = threadIdx.x & 63;
    const int  m    = lane & 31;
    const int  h    = lane >> 5;
    const int  nt32 = N >> 5;             // 6250 tiles of 32 rows
    const long t0   = (long)blockIdx.x * 8;

    auto dma8 = [&](const char* g, char* l) {   // 8 x 1KB coalesced DMA
#pragma unroll
        for (int k = 0; k < 8; ++k) {
            const unsigned p = (unsigned)(k*1024 + lane*16);
            const unsigned y = p ^ (((p >> 8) & 7u) << 4);   // line-preserving
            __builtin_amdgcn_global_load_lds((glb_vp*)(g + y),
                                             (lds_vp*)(l + k*1024), 16, 0, 0);
        }
    };

    // ---------- q prologue: DMA s->A, r->Bb; build hi+lo fragments ----------
    dma8((const char*)s_emb,   A);
    dma8((const char*)rel_emb, Bb);
    asm volatile("s_waitcnt vmcnt(0)" ::: "memory");

    const unsigned fb = (unsigned)(m*256 + h*32);
    const unsigned fs = ((unsigned)(m & 7)) << 4;

    bf16x8 qh[4], ql[4];
    float qn_part = 0.f;
#pragma unroll
    for (int tt = 0; tt < 4; ++tt) {
        const unsigned p = (fb + tt*64) ^ fs;
        float4 s0 = *(const float4*)(A  + p);
        float4 s1 = *(const float4*)(A  + (p ^ 16));
        float4 r0 = *(const float4*)(Bb + p);
        float4 r1 = *(const float4*)(Bb + (p ^ 16));
        const float qf[8] = { s0.x+r0.x, s0.y+r0.y, s0.z+r0.z, s0.w+r0.w,
                              s1.x+r1.x, s1.y+r1.y, s1.z+r1.z, s1.w+r1.w };
#pragma unroll
        for (int i = 0; i < 8; ++i) {
            const float f = qf[i];
            qn_part = fmaf(f, f, qn_part);
            const unsigned u = __float_as_uint(f);
            qh[tt][i] = (short)(u >> 16);                          // trunc hi
            const float lo = f - __uint_as_float(u & 0xFFFF0000u); // exact
            ql[tt][i] = (short)(__float_as_uint(lo) >> 16);
        }
    }
    const float qn_own = qn_part + __shfl_xor(qn_part, 32);
    float qn_all[32];                      // readlane -> wave-uniform SGPRs
#pragma unroll
    for (int i = 0; i < 32; ++i)
        qn_all[i] = __uint_as_float(
            __builtin_amdgcn_readlane(__float_as_uint(qn_own), i));
    asm volatile("s_waitcnt lgkmcnt(0)" ::: "memory");  // q reads done (WAR)

    // ---------- e pipeline: 8 tiles, dbuf, counted vmcnt ----------
    auto stage = [&](long t, char* l) {
        const long ts = (t < nt32) ? t : (long)(nt32 - 1);   // clamp (uniform)
        dma8((const char*)emb_e + ts * 8192, l);
    };
    stage(t0 + 0, A);
    stage(t0 + 1, Bb);

#pragma unroll
    for (int i = 0; i < 8; ++i) {
        if (i < 7) { asm volatile("s_waitcnt vmcnt(8)" ::: "memory"); }
        else       { asm volatile("s_waitcnt vmcnt(0)" ::: "memory"); }
        const char* L = (i & 1) ? Bb : A;

        f32x16 acc;
#pragma unroll
        for (int k = 0; k < 16; ++k) acc[k] = 0.f;
        float en_part = 0.f;
#pragma unroll
        for (int tt = 0; tt < 4; ++tt) {
            const unsigned p = (fb + tt*64) ^ fs;
            float4 e0 = *(const float4*)(L + p);
            float4 e1 = *(const float4*)(L + (p ^ 16));
            en_part = fmaf(e0.x, e0.x, en_part);
            en_part = fmaf(e0.y, e0.y, en_part);
            en_part = fmaf(e0.z, e0.z, en_part);
            en_part = fmaf(e0.w, e0.w, en_part);
            en_part = fmaf(e1.x, e1.x, en_part);
            en_part = fmaf(e1.y, e1.y, en_part);
            en_part = fmaf(e1.z, e1.z, en_part);
            en_part = fmaf(e1.w, e1.w, en_part);
            u32x4 ep;
            ep[0] = __builtin_amdgcn_perm(__float_as_uint(e0.y),
                                          __float_as_uint(e0.x), 0x07060302u);
            ep[1] = __builtin_amdgcn_perm(__float_as_uint(e0.w),
                                          __float_as_uint(e0.z), 0x07060302u);
            ep[2] = __builtin_amdgcn_perm(__float_as_uint(e1.y),
                                          __float_as_uint(e1.x), 0x07060302u);
            ep[3] = __builtin_amdgcn_perm(__float_as_uint(e1.w),
                                          __float_as_uint(e1.z), 0x07060302u);
            const bf16x8 eh = __builtin_bit_cast(bf16x8, ep);
            acc = __builtin_amdgcn_mfma_f32_32x32x16_bf16(qh[tt], eh, acc, 0,0,0);
            acc = __builtin_amdgcn_mfma_f32_32x32x16_bf16(ql[tt], eh, acc, 0,0,0);
        }
        const float en = en_part + __shfl_xor(en_part, 32);   // ||e_{n0+m}||^2

        // epilogue -> oT[b][i*32+m]; 2-way bank alias only (free)
#pragma unroll
        for (int r = 0; r < 16; ++r) {
            const int bb = (r & 3) + 8*(r >> 2);
            const int b  = bb + 4*h;
            const float d2 = fmaxf(fmaf(-2.f, acc[r], qn_all[b] + en), 0.f);
            oT[b*256 + i*32 + m] = MARGIN - sqrtf(d2);
        }

        if (i < 6) {
            // ds_reads of L + oT writes retired before DMA overwrites L
            asm volatile("s_waitcnt lgkmcnt(0)" ::: "memory");
            stage(t0 + i + 2, (char*)L);
        }
    }
    asm volatile("s_waitcnt lgkmcnt(0)" ::: "memory");

    // ---------- store: 32 instrs x 1KB contiguous per output row ----------
    const long nb = t0 * 32;               // this block's n base
#pragma unroll
    for (int rb = 0; rb < 32; ++rb) {
        const long col = nb + lane*4;
        if (col + 3 < N) {                 // masks only in the last block
            const float4 v = *(const float4*)(oT + rb*256 + lane*4);
            *(float4*)(out + (size_t)rb * N + col) = v;
        }
    }
}

extern "C" void kernel_launch(void* const* d_in, const int* in_sizes, int n_in,
                              void* d_out, int out_size, void* d_ws, size_t ws_size,
                              hipStream_t stream) {
    const float* s = (const float*)d_in[0];
    const float* r = (const float*)d_in[1];
    const float* e = (const float*)d_in[2];
    float* out = (float*)d_out;

    const int N = in_sizes[2] / 64;            // 200000
    const int grid = (N + 255) / 256;          // 782 one-wave blocks, 256 n each

    transe10<<<grid, 64, 0, stream>>>(s, r, e, out, N);
}

// Round 11
// 25.548 us; speedup vs baseline: 1.5554x; 1.5554x over previous
//
#include <hip/hip_runtime.h>

// TransE 'rhs': pred[b,n] = MARGIN - ||(s+r)[b] - e[n]||_2. B=32,N=200k,D=64 fp32.
//
// R10 post-mortem: writes clean (25MB) but 1.18TB/s, occ 4.3% -> in-flight
// bytes collapsed (8KB/wave, 3 waves/CU). R11: 2-wave blocks, 256-n span
// (clean stores kept), 3x8KB buffers/wave, counted vmcnt rotation that keeps
// 16-24KB/wave outstanding, preds-in-regs for 4 tiles, outT overlays e-bufs
// after barrier. 6 waves/CU, ~150KB/CU in flight. Frag swizzle widened to
// (m&15) to fix R10's 250K bank-conflict cycles.

#define MARGIN 9.0f

typedef __attribute__((ext_vector_type(8)))  short bf16x8;
typedef __attribute__((ext_vector_type(16))) float f32x16;
typedef __attribute__((ext_vector_type(4)))  unsigned int u32x4;

typedef __attribute__((address_space(3))) void        lds_vp;
typedef __attribute__((address_space(1))) const void  glb_vp;

__device__ __forceinline__ unsigned eswz(unsigned p) {   // involution, in-row
    return p ^ (((p >> 8) & 15u) << 4);                  // spread 16 slots
}

__global__ __launch_bounds__(128)
void transe11(const float* __restrict__ s_emb,
              const float* __restrict__ rel_emb,
              const float* __restrict__ emb_e,
              float* __restrict__ out, int N)
{
    __shared__ __align__(16) char lds[49152];   // 2 waves x 3 x 8KB
    const int t = threadIdx.x, w = t >> 6, lane = t & 63;
    const int m = lane & 31, h = lane >> 5;
    char* const b0 = lds + w * 24576;
    char* const b1 = b0 + 8192;
    char* const b2 = b0 + 16384;
    const int  nt32 = N >> 5;                        // 6250 tiles of 32 rows
    const long T0   = (long)blockIdx.x * 8 + w * 4;  // wave's 4 tiles

    // ---- 1. issue q per-lane loads (block-uniform addr, L2/L3-hot) ----
    const float4* s4 = (const float4*)s_emb;
    const float4* r4 = (const float4*)rel_emb;
    float4 sv[8], rv[8];
#pragma unroll
    for (int k = 0; k < 8; ++k) sv[k] = s4[k*64 + lane];
#pragma unroll
    for (int k = 0; k < 8; ++k) rv[k] = r4[k*64 + lane];

    // ---- 2. issue e-DMA for tiles T1->b1, T2->b2 (in flight early) ----
    auto dma8 = [&](long tile, char* l) {
        const long ts = (tile < nt32) ? tile : (long)(nt32 - 1);
        const char* g = (const char*)emb_e + ts * 8192;
#pragma unroll
        for (int k = 0; k < 8; ++k) {
            const unsigned p = (unsigned)(k*1024 + lane*16);
            __builtin_amdgcn_global_load_lds((glb_vp*)(g + eswz(p)),
                                             (lds_vp*)(l + k*1024), 16, 0, 0);
        }
    };
    dma8(T0 + 1, b1);
    dma8(T0 + 2, b2);

    // ---- 3. q = s + r -> b0 (swizzled), then hi+lo bf16 fragments ----
#pragma unroll
    for (int k = 0; k < 8; ++k) {
        const unsigned p = (unsigned)(k*1024 + lane*16);
        float4 q = make_float4(sv[k].x+rv[k].x, sv[k].y+rv[k].y,
                               sv[k].z+rv[k].z, sv[k].w+rv[k].w);
        *(float4*)(b0 + eswz(p)) = q;
    }
    asm volatile("s_waitcnt lgkmcnt(0)" ::: "memory");

    const unsigned fb = (unsigned)(m*256 + h*32);
    bf16x8 qh[4], ql[4];
    float qn_part = 0.f;
#pragma unroll
    for (int tt = 0; tt < 4; ++tt) {
        const unsigned pe = eswz(fb + tt*64);
        float4 q0 = *(const float4*)(b0 + pe);
        float4 q1 = *(const float4*)(b0 + (pe ^ 16));
        const float qf[8] = {q0.x,q0.y,q0.z,q0.w, q1.x,q1.y,q1.z,q1.w};
#pragma unroll
        for (int i = 0; i < 8; ++i) {
            const float f = qf[i];
            qn_part = fmaf(f, f, qn_part);
            const unsigned u = __float_as_uint(f);
            qh[tt][i] = (short)(u >> 16);                          // trunc hi
            const float lo = f - __uint_as_float(u & 0xFFFF0000u); // exact
            ql[tt][i] = (short)(__float_as_uint(lo) >> 16);
        }
    }
    const float qn_own = qn_part + __shfl_xor(qn_part, 32);
    float qn_all[32];
#pragma unroll
    for (int i = 0; i < 32; ++i)
        qn_all[i] = __uint_as_float(
            __builtin_amdgcn_readlane(__float_as_uint(qn_own), i));

    asm volatile("s_waitcnt lgkmcnt(0)" ::: "memory");  // q reads done (WAR)
    dma8(T0 + 0, b0);                                   // outstanding: 24

    // ---- 4. compute: acc -> preds in place ----
    auto compute_tile = [&](const char* L, f32x16& acc) {
#pragma unroll
        for (int i = 0; i < 16; ++i) acc[i] = 0.f;
        float en_part = 0.f;
#pragma unroll
        for (int tt = 0; tt < 4; ++tt) {
            const unsigned pe = eswz(fb + tt*64);
            float4 e0 = *(const float4*)(L + pe);
            float4 e1 = *(const float4*)(L + (pe ^ 16));
            en_part = fmaf(e0.x, e0.x, en_part);
            en_part = fmaf(e0.y, e0.y, en_part);
            en_part = fmaf(e0.z, e0.z, en_part);
            en_part = fmaf(e0.w, e0.w, en_part);
            en_part = fmaf(e1.x, e1.x, en_part);
            en_part = fmaf(e1.y, e1.y, en_part);
            en_part = fmaf(e1.z, e1.z, en_part);
            en_part = fmaf(e1.w, e1.w, en_part);
            u32x4 ep;
            ep[0] = __builtin_amdgcn_perm(__float_as_uint(e0.y),
                                          __float_as_uint(e0.x), 0x07060302u);
            ep[1] = __builtin_amdgcn_perm(__float_as_uint(e0.w),
                                          __float_as_uint(e0.z), 0x07060302u);
            ep[2] = __builtin_amdgcn_perm(__float_as_uint(e1.y),
                                          __float_as_uint(e1.x), 0x07060302u);
            ep[3] = __builtin_amdgcn_perm(__float_as_uint(e1.w),
                                          __float_as_uint(e1.z), 0x07060302u);
            const bf16x8 eh = __builtin_bit_cast(bf16x8, ep);
            acc = __builtin_amdgcn_mfma_f32_32x32x16_bf16(qh[tt], eh, acc, 0,0,0);
            acc = __builtin_amdgcn_mfma_f32_32x32x16_bf16(ql[tt], eh, acc, 0,0,0);
        }
        const float en = en_part + __shfl_xor(en_part, 32);
#pragma unroll
        for (int r = 0; r < 16; ++r) {
            const int bb = (r & 3) + 8*(r >> 2);
            const float qn_v = h ? qn_all[bb + 4] : qn_all[bb];
            const float d2 = fmaxf(fmaf(-2.f, acc[r], qn_v + en), 0.f);
            acc[r] = MARGIN - sqrtf(d2);
        }
    };

    f32x16 p0, p1, p2, p3;
    asm volatile("s_waitcnt vmcnt(16)" ::: "memory");   // T1 done (T2,T0 fly)
    compute_tile(b1, p1);
    asm volatile("s_waitcnt lgkmcnt(0)" ::: "memory");  // b1 reads retired
    dma8(T0 + 3, b1);                                   // outstanding: 24
    asm volatile("s_waitcnt vmcnt(16)" ::: "memory");   // T2 done (T0,T3 fly)
    compute_tile(b2, p2);
    asm volatile("s_waitcnt vmcnt(8)" ::: "memory");    // T0 done (T3 flies)
    compute_tile(b0, p0);
    asm volatile("s_waitcnt vmcnt(0)" ::: "memory");    // T3 done
    compute_tile(b1, p3);

    // ---- 5. preds -> outT [32 b][256 n] f32 (overlays e-bufs), store ----
    __syncthreads();                    // both waves done reading e-bufs
    float* oT = (float*)lds;
    const int nlb = w*128 + m;
#pragma unroll
    for (int r = 0; r < 16; ++r) {
        const int b = (r & 3) + 8*(r >> 2) + 4*h;
        oT[b*256 + nlb +  0] = p0[r];
        oT[b*256 + nlb + 32] = p1[r];
        oT[b*256 + nlb + 64] = p2[r];
        oT[b*256 + nlb + 96] = p3[r];
    }
    __syncthreads();

    const long nb = (long)blockIdx.x * 256;
#pragma unroll
    for (int k = 0; k < 16; ++k) {      // wave w: rows w*16..w*16+15, 1KB each
        const int  rb  = w*16 + k;
        const long col = nb + lane*4;
        if (col + 3 < N) {
            const float4 v = *(const float4*)(oT + rb*256 + lane*4);
            *(float4*)(out + (size_t)rb * N + col) = v;
        }
    }
}

extern "C" void kernel_launch(void* const* d_in, const int* in_sizes, int n_in,
                              void* d_out, int out_size, void* d_ws, size_t ws_size,
                              hipStream_t stream) {
    const float* s = (const float*)d_in[0];
    const float* r = (const float*)d_in[1];
    const float* e = (const float*)d_in[2];
    float* out = (float*)d_out;

    const int N = in_sizes[2] / 64;            // 200000
    const int grid = (N + 255) / 256;          // 782 blocks x 128 threads

    transe11<<<grid, 128, 0, stream>>>(s, r, e, out, N);
}

// Round 12
// 20.233 us; speedup vs baseline: 1.9640x; 1.2627x over previous
//
#include <hip/hip_runtime.h>

// TransE 'rhs': pred[b,n] = MARGIN - ||(s+r)[b] - e[n]||_2. B=32,N=200k,D=64 fp32.
//
// R11 post-mortem: throughput scales ~linearly with waves/CU (1.2TB/s@3,
// 3.0@6) -> latency-bound, need more issuers; AND 48KB blocks capped
// residency at 768 < 782 grid -> 14-straggler tail (~5us).
// R12: 2 buffers/wave (32KB/block) -> 5 blocks/CU, 10 waves/CU, capacity
// 1280 >= 782 (zero tail). Preds in 64 regs (as R11). Counted vmcnt(8)
// rotation, vmcnt(0) only at last tile. Clean 1KB-row stores kept.

#define MARGIN 9.0f

typedef __attribute__((ext_vector_type(8)))  short bf16x8;
typedef __attribute__((ext_vector_type(16))) float f32x16;
typedef __attribute__((ext_vector_type(4)))  unsigned int u32x4;

typedef __attribute__((address_space(3))) void        lds_vp;
typedef __attribute__((address_space(1))) const void  glb_vp;

__device__ __forceinline__ unsigned eswz(unsigned p) {   // involution, in-row
    return p ^ (((p >> 8) & 15u) << 4);
}

__global__ __launch_bounds__(128, 3)
void transe12(const float* __restrict__ s_emb,
              const float* __restrict__ rel_emb,
              const float* __restrict__ emb_e,
              float* __restrict__ out, int N)
{
    __shared__ __align__(16) char lds[32768];   // 2 waves x 2 x 8KB
    const int t = threadIdx.x, w = t >> 6, lane = t & 63;
    const int m = lane & 31, h = lane >> 5;
    char* const b0 = lds + w * 16384;
    char* const b1 = b0 + 8192;
    const int  nt32 = N >> 5;                        // 6250 tiles of 32 rows
    const long T0   = (long)blockIdx.x * 8 + w * 4;  // wave's 4 tiles

    // ---- 1. q per-lane loads first (oldest in vmcnt FIFO) ----
    const float4* s4 = (const float4*)s_emb;
    const float4* r4 = (const float4*)rel_emb;
    float4 sv[8], rv[8];
#pragma unroll
    for (int k = 0; k < 8; ++k) sv[k] = s4[k*64 + lane];
#pragma unroll
    for (int k = 0; k < 8; ++k) rv[k] = r4[k*64 + lane];

    auto dma8 = [&](long tile, char* l) {            // 8 x 1KB coalesced DMA
        const long ts = (tile < nt32) ? tile : (long)(nt32 - 1);
        const char* g = (const char*)emb_e + ts * 8192;
#pragma unroll
        for (int k = 0; k < 8; ++k) {
            const unsigned p = (unsigned)(k*1024 + lane*16);
            __builtin_amdgcn_global_load_lds((glb_vp*)(g + eswz(p)),
                                             (lds_vp*)(l + k*1024), 16, 0, 0);
        }
    };

    // ---- 2. e-DMA for tile T1 -> b1 (in flight during q work) ----
    dma8(T0 + 1, b1);

    // ---- 3. q = s + r -> b0 (swizzled), hi+lo bf16 fragments ----
#pragma unroll
    for (int k = 0; k < 8; ++k) {
        const unsigned p = (unsigned)(k*1024 + lane*16);
        float4 q = make_float4(sv[k].x+rv[k].x, sv[k].y+rv[k].y,
                               sv[k].z+rv[k].z, sv[k].w+rv[k].w);
        *(float4*)(b0 + eswz(p)) = q;
    }
    asm volatile("s_waitcnt lgkmcnt(0)" ::: "memory");

    const unsigned fb = (unsigned)(m*256 + h*32);
    bf16x8 qh[4], ql[4];
    float qn_part = 0.f;
#pragma unroll
    for (int tt = 0; tt < 4; ++tt) {
        const unsigned pe = eswz(fb + tt*64);
        float4 q0 = *(const float4*)(b0 + pe);
        float4 q1 = *(const float4*)(b0 + (pe ^ 16));
        const float qf[8] = {q0.x,q0.y,q0.z,q0.w, q1.x,q1.y,q1.z,q1.w};
#pragma unroll
        for (int i = 0; i < 8; ++i) {
            const float f = qf[i];
            qn_part = fmaf(f, f, qn_part);
            const unsigned u = __float_as_uint(f);
            qh[tt][i] = (short)(u >> 16);                          // trunc hi
            const float lo = f - __uint_as_float(u & 0xFFFF0000u); // exact
            ql[tt][i] = (short)(__float_as_uint(lo) >> 16);
        }
    }
    const float qn_own = qn_part + __shfl_xor(qn_part, 32);
    float qn_all[32];                      // readlane -> wave-uniform SGPRs
#pragma unroll
    for (int i = 0; i < 32; ++i)
        qn_all[i] = __uint_as_float(
            __builtin_amdgcn_readlane(__float_as_uint(qn_own), i));

    asm volatile("s_waitcnt lgkmcnt(0)" ::: "memory");  // q frag reads done
    dma8(T0 + 0, b0);                                   // FIFO: T1(8), T0(8)

    // ---- 4. compute (preds overwrite acc in place) ----
    auto compute_tile = [&](const char* L, f32x16& acc) {
#pragma unroll
        for (int i = 0; i < 16; ++i) acc[i] = 0.f;
        float en_part = 0.f;
#pragma unroll
        for (int tt = 0; tt < 4; ++tt) {
            const unsigned pe = eswz(fb + tt*64);
            float4 e0 = *(const float4*)(L + pe);
            float4 e1 = *(const float4*)(L + (pe ^ 16));
            en_part = fmaf(e0.x, e0.x, en_part);
            en_part = fmaf(e0.y, e0.y, en_part);
            en_part = fmaf(e0.z, e0.z, en_part);
            en_part = fmaf(e0.w, e0.w, en_part);
            en_part = fmaf(e1.x, e1.x, en_part);
            en_part = fmaf(e1.y, e1.y, en_part);
            en_part = fmaf(e1.z, e1.z, en_part);
            en_part = fmaf(e1.w, e1.w, en_part);
            u32x4 ep;
            ep[0] = __builtin_amdgcn_perm(__float_as_uint(e0.y),
                                          __float_as_uint(e0.x), 0x07060302u);
            ep[1] = __builtin_amdgcn_perm(__float_as_uint(e0.w),
                                          __float_as_uint(e0.z), 0x07060302u);
            ep[2] = __builtin_amdgcn_perm(__float_as_uint(e1.y),
                                          __float_as_uint(e1.x), 0x07060302u);
            ep[3] = __builtin_amdgcn_perm(__float_as_uint(e1.w),
                                          __float_as_uint(e1.z), 0x07060302u);
            const bf16x8 eh = __builtin_bit_cast(bf16x8, ep);
            acc = __builtin_amdgcn_mfma_f32_32x32x16_bf16(qh[tt], eh, acc, 0,0,0);
            acc = __builtin_amdgcn_mfma_f32_32x32x16_bf16(ql[tt], eh, acc, 0,0,0);
        }
        const float en = en_part + __shfl_xor(en_part, 32);
#pragma unroll
        for (int r = 0; r < 16; ++r) {
            const int bb = (r & 3) + 8*(r >> 2);
            const float qn_v = h ? qn_all[bb + 4] : qn_all[bb];
            const float d2 = fmaxf(fmaf(-2.f, acc[r], qn_v + en), 0.f);
            acc[r] = MARGIN - sqrtf(d2);
        }
    };

    f32x16 p0, p1, p2, p3;
    asm volatile("s_waitcnt vmcnt(8)" ::: "memory");    // T1 done, T0 flying
    compute_tile(b1, p1);
    asm volatile("s_waitcnt lgkmcnt(0)" ::: "memory");  // b1 reads retired
    dma8(T0 + 2, b1);                                   // FIFO: T0, T2
    asm volatile("s_waitcnt vmcnt(8)" ::: "memory");    // T0 done, T2 flying
    compute_tile(b0, p0);
    asm volatile("s_waitcnt lgkmcnt(0)" ::: "memory");  // b0 reads retired
    dma8(T0 + 3, b0);                                   // FIFO: T2, T3
    asm volatile("s_waitcnt vmcnt(8)" ::: "memory");    // T2 done, T3 flying
    compute_tile(b1, p2);
    asm volatile("s_waitcnt vmcnt(0)" ::: "memory");    // T3 done
    compute_tile(b0, p3);

    // ---- 5. preds -> outT [32 b][256 n] (overlays e-bufs), clean store ----
    __syncthreads();                    // both waves done reading e-bufs
    float* oT = (float*)lds;
    const int nlb = w*128 + m;
#pragma unroll
    for (int r = 0; r < 16; ++r) {
        const int b = (r & 3) + 8*(r >> 2) + 4*h;
        oT[b*256 + nlb +  0] = p0[r];
        oT[b*256 + nlb + 32] = p1[r];
        oT[b*256 + nlb + 64] = p2[r];
        oT[b*256 + nlb + 96] = p3[r];
    }
    __syncthreads();

    const long nb = (long)blockIdx.x * 256;
#pragma unroll
    for (int k = 0; k < 16; ++k) {      // wave w: rows w*16..w*16+15, 1KB each
        const int  rb  = w*16 + k;
        const long col = nb + lane*4;
        if (col + 3 < N) {
            const float4 v = *(const float4*)(oT + rb*256 + lane*4);
            *(float4*)(out + (size_t)rb * N + col) = v;
        }
    }
}

extern "C" void kernel_launch(void* const* d_in, const int* in_sizes, int n_in,
                              void* d_out, int out_size, void* d_ws, size_t ws_size,
                              hipStream_t stream) {
    const float* s = (const float*)d_in[0];
    const float* r = (const float*)d_in[1];
    const float* e = (const float*)d_in[2];
    float* out = (float*)d_out;

    const int N = in_sizes[2] / 64;            // 200000
    const int grid = (N + 255) / 256;          // 782 blocks x 128 threads

    transe12<<<grid, 128, 0, stream>>>(s, r, e, out, N);
}